// Round 3
// baseline (49.246 us; speedup 1.0000x reference)
//
#include <hip/hip_runtime.h>

#define EPS_F 1e-10f

constexpr int N_CLS = 32;
constexpr int B_SZ  = 2048;
constexpr int D_DIM = 1024;

typedef float f32x4 __attribute__((ext_vector_type(4)));

// One block per b (2048 blocks x 256 threads = 4 waves).
// Wave w owns rows n = w*8 .. w*8+7. Depth-1 software pipeline: prefetch
// row k+1 (nontemporal) while reducing row k. Per-row wave butterfly
// reductions; ss_t reduction folded into row 0's batch.
__global__ __launch_bounds__(256)
void cosine_sim_kernel(const float* __restrict__ s,
                       const float* __restrict__ target,
                       float* __restrict__ out) {
    const int b    = blockIdx.x;
    const int lane = threadIdx.x & 63;
    const int wave = threadIdx.x >> 6;

    // ---- target row: 4 x float4 per lane (L1-cached, shared by 4 waves) ----
    const float4* t4p = reinterpret_cast<const float4*>(target + (size_t)b * D_DIM);
    const float4 t0 = t4p[lane];
    const float4 t1 = t4p[lane + 64];
    const float4 t2 = t4p[lane + 128];
    const float4 t3 = t4p[lane + 192];

    float ss_t;
    {
        float a = fmaf(t0.x, t0.x, fmaf(t0.y, t0.y, fmaf(t0.z, t0.z, t0.w * t0.w)));
        float c = fmaf(t1.x, t1.x, fmaf(t1.y, t1.y, fmaf(t1.z, t1.z, t1.w * t1.w)));
        float d = fmaf(t2.x, t2.x, fmaf(t2.y, t2.y, fmaf(t2.z, t2.z, t2.w * t2.w)));
        float e = fmaf(t3.x, t3.x, fmaf(t3.y, t3.y, fmaf(t3.z, t3.z, t3.w * t3.w)));
        ss_t = (a + c) + (d + e);
    }

    const size_t row_stride4 = (size_t)B_SZ * (D_DIM / 4);  // f32x4 units
    const f32x4* base =
        reinterpret_cast<const f32x4*>(s) +
        ((size_t)(wave * 8) * B_SZ + b) * (size_t)(D_DIM / 4);

    // ---- prefetch row 0 (nontemporal: zero-reuse stream) ----
    f32x4 buf[2][4];
#pragma unroll
    for (int j = 0; j < 4; ++j)
        buf[0][j] = __builtin_nontemporal_load(base + lane + 64 * j);

    float r_t = 0.0f;

#pragma unroll
    for (int k = 0; k < 8; ++k) {
        // prefetch row k+1 before touching row k's data
        if (k < 7) {
            const f32x4* pn = base + (size_t)(k + 1) * row_stride4;
#pragma unroll
            for (int j = 0; j < 4; ++j)
                buf[(k + 1) & 1][j] = __builtin_nontemporal_load(pn + lane + 64 * j);
        }

        const f32x4 v0 = buf[k & 1][0];
        const f32x4 v1 = buf[k & 1][1];
        const f32x4 v2 = buf[k & 1][2];
        const f32x4 v3 = buf[k & 1][3];

        float d = fmaf(t0.x, v0.x, fmaf(t0.y, v0.y, fmaf(t0.z, v0.z, t0.w * v0.w)));
        d = fmaf(t1.x, v1.x, fmaf(t1.y, v1.y, fmaf(t1.z, v1.z, fmaf(t1.w, v1.w, d))));
        d = fmaf(t2.x, v2.x, fmaf(t2.y, v2.y, fmaf(t2.z, v2.z, fmaf(t2.w, v2.w, d))));
        d = fmaf(t3.x, v3.x, fmaf(t3.y, v3.y, fmaf(t3.z, v3.z, fmaf(t3.w, v3.w, d))));

        float q = fmaf(v0.x, v0.x, fmaf(v0.y, v0.y, fmaf(v0.z, v0.z, v0.w * v0.w)));
        q = fmaf(v1.x, v1.x, fmaf(v1.y, v1.y, fmaf(v1.z, v1.z, fmaf(v1.w, v1.w, q))));
        q = fmaf(v2.x, v2.x, fmaf(v2.y, v2.y, fmaf(v2.z, v2.z, fmaf(v2.w, v2.w, q))));
        q = fmaf(v3.x, v3.x, fmaf(v3.y, v3.y, fmaf(v3.z, v3.z, fmaf(v3.w, v3.w, q))));

        if (k == 0) {
            // 3 interleaved butterfly chains: dot, ssq, ss_t
#pragma unroll
            for (int off = 32; off >= 1; off >>= 1) {
                d    += __shfl_xor(d,    off, 64);
                q    += __shfl_xor(q,    off, 64);
                ss_t += __shfl_xor(ss_t, off, 64);
            }
            r_t = 1.0f / sqrtf(fmaxf(ss_t, EPS_F));
        } else {
#pragma unroll
            for (int off = 32; off >= 1; off >>= 1) {
                d += __shfl_xor(d, off, 64);
                q += __shfl_xor(q, off, 64);
            }
        }

        if (lane == 0) {
            out[b * N_CLS + wave * 8 + k] =
                d * r_t * (1.0f / sqrtf(fmaxf(q, EPS_F)));
        }
    }
}

extern "C" void kernel_launch(void* const* d_in, const int* in_sizes, int n_in,
                              void* d_out, int out_size, void* d_ws, size_t ws_size,
                              hipStream_t stream) {
    const float* s      = (const float*)d_in[0];   // [N, B, D] f32
    const float* target = (const float*)d_in[1];   // [B, D] f32
    // d_in[2] = s_label (int64) — unused by the reference output.
    float* out = (float*)d_out;                    // [B, N] f32

    hipLaunchKernelGGL(cosine_sim_kernel, dim3(B_SZ), dim3(256), 0, stream,
                       s, target, out);
}

// Round 4
// 46.932 us; speedup vs baseline: 1.0493x; 1.0493x over previous
//
#include <hip/hip_runtime.h>

#define EPS_F 1e-10f

constexpr int N_CLS = 32;
constexpr int B_SZ  = 2048;
constexpr int D_DIM = 1024;

// Round-1 structure (best measured: 46.1 us = 5.73 TB/s effective).
// One block per b (2048 blocks x 256 threads = 4 waves = 32 waves/CU).
// Wave w owns rows n = w*8 .. w*8+7; simple per-row loop, per-row wave
// butterfly reduction. TLP (8 blocks/CU) hides reduce-chain latency;
// explicit SW pipelining / nt loads / deferred reductions all regressed
// (rounds 2-3: 49.1/49.2 us) -- the scheduler already saturates VMEM.
__global__ __launch_bounds__(256)
void cosine_sim_kernel(const float* __restrict__ s,
                       const float* __restrict__ target,
                       float* __restrict__ out) {
    const int b    = blockIdx.x;
    const int lane = threadIdx.x & 63;
    const int wave = threadIdx.x >> 6;

    // ---- load target row into registers: 4 x float4 per lane (covers D=1024) ----
    const float4* t4p = reinterpret_cast<const float4*>(target + (size_t)b * D_DIM);
    float4 t[4];
    float ss_t = 0.0f;
#pragma unroll
    for (int j = 0; j < 4; ++j) {
        t[j] = t4p[lane + 64 * j];
        ss_t = fmaf(t[j].x, t[j].x,
               fmaf(t[j].y, t[j].y,
               fmaf(t[j].z, t[j].z,
               fmaf(t[j].w, t[j].w, ss_t))));
    }
    // wave64 butterfly reduce
#pragma unroll
    for (int off = 32; off >= 1; off >>= 1) ss_t += __shfl_xor(ss_t, off, 64);
    const float r_t = 1.0f / sqrtf(fmaxf(ss_t, EPS_F));

    // ---- 8 rows of s per wave ----
    for (int k = 0; k < 8; ++k) {
        const int n = wave * 8 + k;
        const float4* s4p =
            reinterpret_cast<const float4*>(s + ((size_t)n * B_SZ + b) * (size_t)D_DIM);
        float dot = 0.0f, ss = 0.0f;
#pragma unroll
        for (int j = 0; j < 4; ++j) {
            const float4 v = s4p[lane + 64 * j];
            dot = fmaf(t[j].x, v.x,
                  fmaf(t[j].y, v.y,
                  fmaf(t[j].z, v.z,
                  fmaf(t[j].w, v.w, dot))));
            ss  = fmaf(v.x, v.x,
                  fmaf(v.y, v.y,
                  fmaf(v.z, v.z,
                  fmaf(v.w, v.w, ss))));
        }
#pragma unroll
        for (int off = 32; off >= 1; off >>= 1) {
            dot += __shfl_xor(dot, off, 64);
            ss  += __shfl_xor(ss,  off, 64);
        }
        if (lane == 0) {
            const float r_s = 1.0f / sqrtf(fmaxf(ss, EPS_F));
            out[(size_t)b * N_CLS + n] = dot * r_t * r_s;
        }
    }
}

extern "C" void kernel_launch(void* const* d_in, const int* in_sizes, int n_in,
                              void* d_out, int out_size, void* d_ws, size_t ws_size,
                              hipStream_t stream) {
    const float* s      = (const float*)d_in[0];   // [N, B, D] f32
    const float* target = (const float*)d_in[1];   // [B, D] f32
    // d_in[2] = s_label (int64) — unused by the reference output.
    float* out = (float*)d_out;                    // [B, N] f32

    hipLaunchKernelGGL(cosine_sim_kernel, dim3(B_SZ), dim3(256), 0, stream,
                       s, target, out);
}